// Round 11
// baseline (67.539 us; speedup 1.0000x reference)
//
#include <hip/hip_runtime.h>
#include <math.h>
#include <stdint.h>

#define KK 5
#define PADK 2
#define C_IN 8
#define O_OUT 8
#define HH 512
#define WW 512
#define TH 8
#define TW 128
#define CH 4                      // channels per staged half
#define LROWS 12                  // TH + 4
#define LCOLS 136                 // TW + 4 halo, padded (f32 cols)
#define WSTR 12                   // dwords per (c,dy,og) chunk: 10 used, 48 B
#define NW (O_OUT * C_IN * KK * KK)   // 1600
#define XHALF (CH * LROWS * (LCOLS / 2))   // float2 slots per half = 3264

// Full-rate VOP3 3-input max.
static __device__ __forceinline__ float max3f(float a, float b, float c) {
    float d;
    asm("v_max3_f32 %0, %1, %2, %3" : "=v"(d) : "v"(a), "v"(b), "v"(c));
    return d;
}

__global__ __launch_bounds__(512, 8)
void dil_kernel(const float* __restrict__ x,
                const float* __restrict__ wf,
                float* __restrict__ out) {
    __shared__ __align__(16) float xlds[CH][LROWS][LCOLS];          // 26,112 B
    __shared__ __align__(16) float wlds[C_IN * KK * 4 * WSTR];      //  7,680 B

    const int tid = threadIdx.x;
    const int w0 = blockIdx.x * TW;
    const int h0 = blockIdx.y * TH;
    const int n  = blockIdx.z;
    const float* xn = x + (size_t)n * (C_IN * HH * WW);

    // wave -> one output row; lane -> 2-pixel strip; each wave does all 8 o
    const int l   = tid & 63;
    const int wid = tid >> 6;          // 0..7 = row in tile

    float acc[O_OUT][2];
    #pragma unroll
    for (int o = 0; o < O_OUT; ++o) {
        acc[o][0] = -INFINITY;
        acc[o][1] = -INFINITY;
    }

    for (int h = 0; h < 2; ++h) {
        if (h) __syncthreads();        // all waves done with xlds half 0

        // ---- stage x half (4 channels), zero halo == reference zero pad ----
        for (int idx = tid; idx < XHALF; idx += 512) {
            int cc  = idx / (LROWS * (LCOLS / 2));
            int rem = idx - cc * (LROWS * (LCOLS / 2));
            int r   = rem / (LCOLS / 2);
            int jp  = rem - r * (LCOLS / 2);
            int gh = h0 - PADK + r;
            int gw = w0 - PADK + 2 * jp;
            float v0 = 0.f, v1 = 0.f;
            if ((unsigned)gh < (unsigned)HH) {
                const float* row = xn + ((size_t)(h * CH + cc) * HH + gh) * WW;
                if ((unsigned)gw < (unsigned)WW) v0 = row[gw];
                if ((unsigned)(gw + 1) < (unsigned)WW) v1 = row[gw + 1];
            }
            *(float2*)&xlds[cc][r][2 * jp] = make_float2(v0, v1);
        }
        // ---- stage weights once: layout [c][dy][og][o2*5+dx] ----
        if (h == 0) {
            for (int t = tid; t < NW; t += 512) {
                int dx = t % KK;  int q = t / KK;
                int o2 = q & 1;   q >>= 1;
                int dy = q % KK;  q /= KK;
                int g  = q & 3;   int c = q >> 2;
                int o = g * 2 + o2;
                wlds[((c * KK + dy) * 4 + g) * WSTR + o2 * KK + dx] =
                    wf[((o * C_IN + c) * KK + dy) * KK + dx];
            }
        }
        __syncthreads();

        for (int cc = 0; cc < CH; ++cc) {
            const int c = h * CH + cc;
            #pragma unroll
            for (int dy = 0; dy < KK; ++dy) {
                // ONE x row per (c,dy): 6-wide window, 3x ds_read_b64
                const float* lr = &xlds[cc][wid + dy][2 * l];
                float2 a = *(const float2*)(lr);
                float2 b = *(const float2*)(lr + 2);
                float2 d = *(const float2*)(lr + 4);
                const float u0 = a.x, u1 = a.y, u2 = b.x,
                            u3 = b.y, u4 = d.x, u5 = d.y;
                const float* wdy = &wlds[(c * KK + dy) * 4 * WSTR];
                #pragma unroll
                for (int g = 0; g < 4; ++g) {
                    // 10 wave-uniform weight dwords (broadcast reads)
                    const float* wch = wdy + g * WSTR;
                    float4 wa = *(const float4*)(wch);
                    float4 wv = *(const float4*)(wch + 4);
                    float2 wc2 = *(const float2*)(wch + 8);
                    const float w[10] = {wa.x, wa.y, wa.z, wa.w,
                                         wv.x, wv.y, wv.z, wv.w,
                                         wc2.x, wc2.y};
                    #pragma unroll
                    for (int o2 = 0; o2 < 2; ++o2) {
                        const int o = g * 2 + o2;
                        const float* wo = &w[o2 * 5];
                        // pixel 0: window u0..u4
                        float t0 = u0 + wo[0], t1 = u1 + wo[1],
                              t2 = u2 + wo[2], t3 = u3 + wo[3],
                              t4 = u4 + wo[4];
                        acc[o][0] = max3f(acc[o][0],
                                          max3f(t0, t1, t2),
                                          fmaxf(t3, t4));
                        // pixel 1: window u1..u5
                        float s0 = u1 + wo[0], s1 = u2 + wo[1],
                              s2 = u3 + wo[2], s3 = u4 + wo[3],
                              s4 = u5 + wo[4];
                        acc[o][1] = max3f(acc[o][1],
                                          max3f(s0, s1, s2),
                                          fmaxf(s3, s4));
                    }
                }
            }
        }
    }

    // ---- store: 2 consecutive pixels -> one float2, coalesced ----
    float* onp = out + (size_t)n * (O_OUT * HH * WW);
    const int hB = h0 + wid;
    const int wcol = w0 + 2 * l;
    #pragma unroll
    for (int o = 0; o < O_OUT; ++o) {
        float2 rr = make_float2(acc[o][0], acc[o][1]);
        *(float2*)(&onp[((size_t)o * HH + hB) * WW + wcol]) = rr;
    }
}

extern "C" void kernel_launch(void* const* d_in, const int* in_sizes, int n_in,
                              void* d_out, int out_size, void* d_ws, size_t ws_size,
                              hipStream_t stream) {
    const float* x   = (const float*)d_in[0];
    const float* wgt = (const float*)d_in[1];
    float* out = (float*)d_out;

    dim3 grid(WW / TW, HH / TH, 4);   // (4, 64, 4) = 1024 blocks x 512 thr
    dim3 block(512);
    dil_kernel<<<grid, block, 0, stream>>>(x, wgt, out);
}

// Round 12
// 67.036 us; speedup vs baseline: 1.0075x; 1.0075x over previous
//
#include <hip/hip_runtime.h>
#include <math.h>
#include <stdint.h>

#define KK 5
#define PADK 2
#define C_IN 8
#define O_OUT 8
#define HH 512
#define WW 512
#define TH 16
#define TW 128
#define CH 2                      // channels per staged phase
#define LROWS 20                  // TH + 4
#define LCOLS 136                 // TW + 4 halo, padded (f32 cols)
#define WSTR 12                   // dwords per (c,dy,og) chunk: 10 used, 48 B
#define NW (O_OUT * C_IN * KK * KK)   // 1600
#define XQ (CH * LROWS * (LCOLS / 2))  // float2 slots per phase = 2720

// Full-rate VOP3 3-input max.
static __device__ __forceinline__ float max3f(float a, float b, float c) {
    float d;
    asm("v_max3_f32 %0, %1, %2, %3" : "=v"(d) : "v"(a), "v"(b), "v"(c));
    return d;
}

__global__ __launch_bounds__(512, 4)
void dil_kernel(const float* __restrict__ x,
                const float* __restrict__ wf,
                float* __restrict__ out) {
    __shared__ __align__(16) float xlds[CH][LROWS][LCOLS];        // 21,760 B
    __shared__ __align__(16) float wlds[C_IN * KK * 4 * WSTR];    //  7,680 B

    const int tid = threadIdx.x;
    const int w0 = blockIdx.x * TW;
    const int h0 = blockIdx.y * TH;
    const int n  = blockIdx.z;
    const float* xn = x + (size_t)n * (C_IN * HH * WW);

    // lane -> 4-pixel strip; half-wave -> row; wave -> 2 rows; 8 waves = 16 rows
    const int l   = tid & 63;
    const int s   = l & 31;            // strip: pixels 4s..4s+3
    const int hw  = l >> 5;            // half-wave row select
    const int wid = tid >> 6;          // 0..7
    const int loc = wid * 2 + hw;      // local output row 0..15

    float acc[O_OUT][4];
    #pragma unroll
    for (int o = 0; o < O_OUT; ++o)
        #pragma unroll
        for (int p = 0; p < 4; ++p) acc[o][p] = -INFINITY;

    for (int ph = 0; ph < C_IN / CH; ++ph) {
        if (ph) __syncthreads();       // all waves done with previous phase

        // ---- stage CH channels (f32, zero halo == reference zero pad) ----
        for (int idx = tid; idx < XQ; idx += 512) {
            int cc  = idx / (LROWS * (LCOLS / 2));
            int rem = idx - cc * (LROWS * (LCOLS / 2));
            int r   = rem / (LCOLS / 2);
            int jp  = rem - r * (LCOLS / 2);
            int gh = h0 - PADK + r;
            int gw = w0 - PADK + 2 * jp;
            float v0 = 0.f, v1 = 0.f;
            if ((unsigned)gh < (unsigned)HH) {
                const float* row = xn + ((size_t)(ph * CH + cc) * HH + gh) * WW;
                if ((unsigned)gw < (unsigned)WW) v0 = row[gw];
                if ((unsigned)(gw + 1) < (unsigned)WW) v1 = row[gw + 1];
            }
            *(float2*)&xlds[cc][r][2 * jp] = make_float2(v0, v1);
        }
        // ---- stage weights once: layout [c][dy][og][o2*5+dx] ----
        if (ph == 0) {
            for (int t = tid; t < NW; t += 512) {
                int dx = t % KK;  int q = t / KK;
                int o2 = q & 1;   q >>= 1;
                int dy = q % KK;  q /= KK;
                int g  = q & 3;   int c = q >> 2;
                int o = g * 2 + o2;
                wlds[((c * KK + dy) * 4 + g) * WSTR + o2 * KK + dx] =
                    wf[((o * C_IN + c) * KK + dy) * KK + dx];
            }
        }
        __syncthreads();

        for (int cc = 0; cc < CH; ++cc) {
            const int c = ph * CH + cc;
            #pragma unroll
            for (int dy = 0; dy < KK; ++dy) {
                // ONE row window per (c,dy): 8 floats, 2x ds_read_b128
                const float* lr = &xlds[cc][loc + dy][4 * s];
                float4 A = *(const float4*)(lr);
                float4 B = *(const float4*)(lr + 4);
                const float u[8] = {A.x, A.y, A.z, A.w, B.x, B.y, B.z, B.w};
                const float* wdy = &wlds[(c * KK + dy) * 4 * WSTR];
                #pragma unroll
                for (int og = 0; og < 4; ++og) {
                    // 10 wave-uniform weight dwords (broadcast reads)
                    const float* wch = wdy + og * WSTR;
                    float4 wa = *(const float4*)(wch);
                    float4 wb = *(const float4*)(wch + 4);
                    float2 wc2 = *(const float2*)(wch + 8);
                    const float w[10] = {wa.x, wa.y, wa.z, wa.w,
                                         wb.x, wb.y, wb.z, wb.w,
                                         wc2.x, wc2.y};
                    #pragma unroll
                    for (int o2 = 0; o2 < 2; ++o2) {
                        const int o = og * 2 + o2;
                        const float* wo = &w[o2 * 5];
                        #pragma unroll
                        for (int p = 0; p < 4; ++p) {
                            float t0 = u[p + 0] + wo[0];
                            float t1 = u[p + 1] + wo[1];
                            float t2 = u[p + 2] + wo[2];
                            float t3 = u[p + 3] + wo[3];
                            float t4 = u[p + 4] + wo[4];
                            acc[o][p] = max3f(acc[o][p],
                                              max3f(t0, t1, t2),
                                              fmaxf(t3, t4));
                        }
                    }
                }
            }
        }
    }

    // ---- store: 4 consecutive pixels -> one float4, coalesced ----
    float* onp = out + (size_t)n * (O_OUT * HH * WW);
    const int h = h0 + loc;
    const int col = w0 + 4 * s;
    #pragma unroll
    for (int o = 0; o < O_OUT; ++o) {
        float4 rr = make_float4(acc[o][0], acc[o][1], acc[o][2], acc[o][3]);
        *(float4*)(&onp[((size_t)o * HH + h) * WW + col]) = rr;
    }
}

extern "C" void kernel_launch(void* const* d_in, const int* in_sizes, int n_in,
                              void* d_out, int out_size, void* d_ws, size_t ws_size,
                              hipStream_t stream) {
    const float* x   = (const float*)d_in[0];
    const float* wgt = (const float*)d_in[1];
    float* out = (float*)d_out;

    dim3 grid(WW / TW, HH / TH, 4);   // (4, 32, 4) = 512 blocks x 512 thr
    dim3 block(512);
    dil_kernel<<<grid, block, 0, stream>>>(x, wgt, out);
}